// Round 4
// baseline (214.761 us; speedup 1.0000x reference)
//
#include <hip/hip_runtime.h>
#include <math.h>

#define L 256
#define E 128
#define H 4
#define C 32
#define P (L*L)  // 65536

typedef __bf16 bf16;
typedef __bf16 bf16x8 __attribute__((ext_vector_type(8)));
typedef __bf16 bf16x4 __attribute__((ext_vector_type(4)));
typedef float  f32x4  __attribute__((ext_vector_type(4)));

#define MFMA(a,b,c) __builtin_amdgcn_mfma_f32_16x16x32_bf16((a),(b),(c),0,0,0)

// ---------------------------------------------------------------------------
// k_prep: weights in MFMA A-fragment order. frag f=mt*4+kt; elem j at lane
// (g,l15) is A[row=16mt+l15][k=32kt+8g+j] = W[k][row] (*C^-0.5 for Wq).
// ---------------------------------------------------------------------------
__global__ __launch_bounds__(256) void k_prep(
    const float* __restrict__ Wq, const float* __restrict__ Wk,
    const float* __restrict__ Wv, const float* __restrict__ Wfu,
    const float* __restrict__ Wo, const float* __restrict__ Wb,
    bf16* __restrict__ WF, bf16* __restrict__ WoF, bf16* __restrict__ WbF)
{
  const int m = blockIdx.x;  // 0..5
  const int lane = threadIdx.x & 63, wv = threadIdx.x >> 6;
  const int g = lane >> 4, l15 = lane & 15;
  if (m < 5) {
    const float* W = (m==0)?Wq:(m==1)?Wk:(m==2)?Wv:(m==3)?Wfu:Wo;
    bf16* dst = (m < 4) ? (WF + (size_t)m * 16384) : WoF;
    const float sc = (m == 0) ? 0.17677669529663689f : 1.0f;
    for (int f = wv; f < 32; f += 4) {
      const int mt = f >> 2, kt = f & 3;
      const int row = 16*mt + l15, k0 = 32*kt + 8*g;
      bf16x8 o;
      #pragma unroll
      for (int j = 0; j < 8; ++j) o[j] = (bf16)(W[(size_t)(k0+j)*128 + row] * sc);
      *(bf16x8*)(dst + ((size_t)f*64 + lane)*8) = o;
    }
  } else {
    const int kt = wv, k0 = 32*kt + 8*g;
    bf16x8 o;
    #pragma unroll
    for (int j = 0; j < 8; ++j)
      o[j] = (l15 < 4) ? (bf16)Wb[(size_t)(k0+j)*4 + l15] : (bf16)0.0f;
    *(bf16x8*)(WbF + ((size_t)kt*64 + lane)*8) = o;
  }
}

// ---------------------------------------------------------------------------
// k_ln_proj: LN -> bf16 x in LDS; per-wave matrix (q,k,v,gate) via MFMA.
// 32 positions per pass (A-frags loaded once per 2 output subtiles).
// wave 2 emits v in PV-fragment order vF[h][s][f][lane][8]; waves 0/1 write
// head-major q/k; wave 3 writes gate row-major. pb planar [h][P] fp32.
// ---------------------------------------------------------------------------
__global__ __launch_bounds__(256) void k_ln_proj(
    const float* __restrict__ pr, const float* __restrict__ gamma,
    const float* __restrict__ beta, const float* __restrict__ bfu,
    const bf16* __restrict__ WF, const bf16* __restrict__ WbF,
    bf16* __restrict__ qbh, bf16* __restrict__ kbh, bf16* __restrict__ vF,
    bf16* __restrict__ gfb, float* __restrict__ pbo)
{
  __shared__ bf16 xs[64 * 136];        // 17.0 KB
  __shared__ bf16 stag[4][32 * 132];   // 33.8 KB
  const int tid = threadIdx.x;
  const int base = blockIdx.x * 64;
  const int sblk = blockIdx.x >> 2;

  // --- LayerNorm (4 threads per position) ---
  {
    const int pl = tid >> 2, sub = tid & 3;
    const float4* src = (const float4*)(pr + (size_t)(base + pl) * 128 + sub * 32);
    float4 r[8];
    float s = 0.f, ss = 0.f;
    #pragma unroll
    for (int j = 0; j < 8; ++j) {
      r[j] = src[j];
      s  += r[j].x + r[j].y + r[j].z + r[j].w;
      ss += r[j].x*r[j].x + r[j].y*r[j].y + r[j].z*r[j].z + r[j].w*r[j].w;
    }
    s  += __shfl_xor(s, 1, 4);  s  += __shfl_xor(s, 2, 4);
    ss += __shfl_xor(ss, 1, 4); ss += __shfl_xor(ss, 2, 4);
    const float mu   = s * 0.0078125f;
    const float var  = ss * 0.0078125f - mu * mu;
    const float rstd = rsqrtf(var + 1e-5f);
    const float4* g4 = (const float4*)(gamma + sub * 32);
    const float4* b4 = (const float4*)(beta + sub * 32);
    bf16* xr = xs + pl * 136 + sub * 32;
    #pragma unroll
    for (int i = 0; i < 4; ++i) {
      float4 r0 = r[2*i], r1 = r[2*i+1];
      float4 gg0 = g4[2*i], gg1 = g4[2*i+1], bb0 = b4[2*i], bb1 = b4[2*i+1];
      bf16x8 o;
      o[0] = (bf16)((r0.x - mu) * rstd * gg0.x + bb0.x);
      o[1] = (bf16)((r0.y - mu) * rstd * gg0.y + bb0.y);
      o[2] = (bf16)((r0.z - mu) * rstd * gg0.z + bb0.z);
      o[3] = (bf16)((r0.w - mu) * rstd * gg0.w + bb0.w);
      o[4] = (bf16)((r1.x - mu) * rstd * gg1.x + bb1.x);
      o[5] = (bf16)((r1.y - mu) * rstd * gg1.y + bb1.y);
      o[6] = (bf16)((r1.z - mu) * rstd * gg1.z + bb1.z);
      o[7] = (bf16)((r1.w - mu) * rstd * gg1.w + bb1.w);
      *(bf16x8*)(xr + 8 * i) = o;
    }
  }
  __syncthreads();

  const int w = tid >> 6, lane = tid & 63, g = lane >> 4, l15 = lane & 15;
  const f32x4 z = {0.f, 0.f, 0.f, 0.f};

  // --- pair_bias via MFMA: wave w -> positions base+16w .. base+16w+15 ---
  {
    f32x4 acc = z;
    #pragma unroll
    for (int kt = 0; kt < 4; ++kt) {
      bf16x8 a = *(const bf16x8*)(WbF + ((size_t)kt*64 + lane)*8);
      bf16x8 b = *(const bf16x8*)(xs + (16*w + l15)*136 + 32*kt + 8*g);
      acc = MFMA(a, b, acc);
    }
    if (g == 0) {
      #pragma unroll
      for (int r = 0; r < 4; ++r)
        pbo[(size_t)r*P + base + 16*w + l15] = acc[r];
    }
  }

  // --- projection: wave w -> matrix w; 32 positions per pass ---
  const bf16* WFw = WF + (size_t)w * 16384;
  bf16* stw = stag[w];

  for (int ntp = 0; ntp < 2; ++ntp) {
    bf16x8 bfr[2][4];
    #pragma unroll
    for (int p = 0; p < 2; ++p)
      #pragma unroll
      for (int kt = 0; kt < 4; ++kt)
        bfr[p][kt] = *(const bf16x8*)(xs + (32*ntp + 16*p + l15)*136 + 32*kt + 8*g);

    f32x4 acc[8][2];
    #pragma unroll
    for (int mt = 0; mt < 8; ++mt) { acc[mt][0] = z; acc[mt][1] = z; }
    #pragma unroll
    for (int kt = 0; kt < 4; ++kt)
      #pragma unroll
      for (int mt = 0; mt < 8; ++mt) {
        bf16x8 a = *(const bf16x8*)(WFw + ((size_t)(mt*4 + kt)*64 + lane)*8);
        acc[mt][0] = MFMA(a, bfr[0][kt], acc[mt][0]);
        acc[mt][1] = MFMA(a, bfr[1][kt], acc[mt][1]);
      }

    // epilogue -> LDS staging: stw[pos_in_pair(32)][col(128), stride 132]
    #pragma unroll
    for (int mt = 0; mt < 8; ++mt) {
      const int col = 16*mt + 4*g;
      #pragma unroll
      for (int p = 0; p < 2; ++p) {
        f32x4 vv = acc[mt][p];
        if (w == 3) {
          float4 bb = *(const float4*)(bfu + col);
          vv[0] = 1.f / (1.f + __expf(-(vv[0] + bb.x)));
          vv[1] = 1.f / (1.f + __expf(-(vv[1] + bb.y)));
          vv[2] = 1.f / (1.f + __expf(-(vv[2] + bb.z)));
          vv[3] = 1.f / (1.f + __expf(-(vv[3] + bb.w)));
        }
        bf16x4 o;
        o[0] = (bf16)vv[0]; o[1] = (bf16)vv[1]; o[2] = (bf16)vv[2]; o[3] = (bf16)vv[3];
        *(bf16x4*)(stw + (16*p + l15)*132 + col) = o;
      }
    }

    if (w == 2) {
      // v in PV-fragment order: this 32-pos window is kt tile ktg of row sblk
      const int ktg = (blockIdx.x & 3)*2 + ntp;
      #pragma unroll
      for (int h = 0; h < 4; ++h)
        #pragma unroll
        for (int mt2 = 0; mt2 < 2; ++mt2) {
          bf16x8 o;
          #pragma unroll
          for (int j = 0; j < 8; ++j)
            o[j] = stw[(8*(lane >> 4) + j)*132 + h*32 + 16*mt2 + (lane & 15)];
          *(bf16x8*)(vF + (((size_t)(h*256 + sblk)*16 + mt2*8 + ktg)*64 + lane)*8) = o;
        }
    } else {
      #pragma unroll
      for (int i = 0; i < 8; ++i) {
        const int flat = i*512 + lane*8;
        const int p2 = flat >> 7, c = flat & 127;
        bf16x8 val = *(const bf16x8*)(stw + p2*132 + c);
        if (w == 3) {
          *(bf16x8*)(gfb + ((size_t)(base + 32*ntp + p2))*128 + c) = val;
        } else {
          bf16* dst = (w == 0) ? qbh : kbh;
          const int h2 = c >> 5;
          *(bf16x8*)(dst + ((size_t)h2*P + base + 32*ntp + p2)*32 + (c & 31)) = val;
        }
      }
    }
  }
}

// ---------------------------------------------------------------------------
// k_bias6: T6[h][qblk(16)][t(16)][lane(64)][4] = mask[q,v] + pb[h][q*256+v]
// with q = qblk*16 + (lane&15), v = 16t + 4*(lane>>4) + r. Coalesced b64 out.
// grid 64 = h*16 + qblk; 256 threads = 4 t-groups x 64 lanes.
// ---------------------------------------------------------------------------
__global__ __launch_bounds__(256) void k_bias6(
    const float* __restrict__ mask, const float* __restrict__ pb,
    bf16* __restrict__ T6)
{
  const int b = blockIdx.x, h = b >> 4;
  const int lane = threadIdx.x & 63, tg = threadIdx.x >> 6;
  const int g = lane >> 4, l15 = lane & 15;
  const int q = (b & 15)*16 + l15;
  const float* mrow = mask + (size_t)q * 256;
  const float* prow = pb + (size_t)h * P + (size_t)q * 256;
  #pragma unroll
  for (int tt = 0; tt < 4; ++tt) {
    const int t = tg*4 + tt, v0 = 16*t + 4*g;
    float4 m4 = *(const float4*)(mrow + v0);
    float4 p4 = *(const float4*)(prow + v0);
    bf16x4 o;
    o[0] = (bf16)(m4.x + p4.x); o[1] = (bf16)(m4.y + p4.y);
    o[2] = (bf16)(m4.z + p4.z); o[3] = (bf16)(m4.w + p4.w);
    *(bf16x4*)(T6 + (((size_t)b*16 + t)*64 + lane)*4) = o;
  }
}

// ---------------------------------------------------------------------------
// k_attn: block=(s,h), 4 waves x 64 q-rows. No barriers, no staging.
// QK^T with A=qhat (m=v, hoisted regs), B=k (n=q). Each lane's D-values share
// one q => 2-shuffle row-sum, b64 P-stores. PV: A=vF (coalesced), B=P (LDS).
// ---------------------------------------------------------------------------
__global__ __launch_bounds__(256) void k_attn(
    const bf16* __restrict__ qbh, const bf16* __restrict__ kbh,
    const bf16* __restrict__ vF, const bf16* __restrict__ T6,
    bf16* __restrict__ aob)
{
  __shared__ bf16 ps[4][16 * 264];    // 33.8 KB
  const int tid = threadIdx.x;
  const int s = blockIdx.x >> 2, h = blockIdx.x & 3;
  const int rb = s * 256;
  const int w = tid >> 6, lane = tid & 63, g = lane >> 4, l15 = lane & 15;
  const bf16* qh = qbh + (size_t)h * P * 32;
  const bf16* kh = kbh + (size_t)h * P * 32;
  const bf16* vFh = vF + ((size_t)(h*256 + s)*16)*512;
  bf16* psw = ps[w];
  bf16* aoh = aob + (size_t)h * P * 32;
  const f32x4 z = {0.f, 0.f, 0.f, 0.f};

  // hoist qhat A-fragments (m = v-dim): aq[t] covers v rows 16t..16t+15
  bf16x8 aq[16];
  #pragma unroll
  for (int t = 0; t < 16; ++t)
    aq[t] = *(const bf16x8*)(qh + ((size_t)rb + 16*t + l15)*32 + 8*g);

  for (int qt = 0; qt < 4; ++qt) {
    const int q0 = w*64 + qt*16;

    // B = k for 16 q rows
    bf16x8 bk = *(const bf16x8*)(kh + ((size_t)rb + q0 + l15)*32 + 8*g);

    // scores: D[m=v=16t+4g+r][n=q=q0+l15]
    f32x4 sc[16];
    #pragma unroll
    for (int t = 0; t < 16; ++t) sc[t] = MFMA(aq[t], bk, z);

    // bias (coalesced b64) + exp + row sum (all values in a lane share q)
    const bf16* Tq = T6 + ((size_t)(h*16 + w*4 + qt)*16)*256;
    float rs = 0.f;
    #pragma unroll
    for (int t = 0; t < 16; ++t) {
      bf16x4 bb = *(const bf16x4*)(Tq + ((size_t)t*64 + lane)*4);
      float e0 = __expf(sc[t][0] + (float)bb[0]);
      float e1 = __expf(sc[t][1] + (float)bb[1]);
      float e2 = __expf(sc[t][2] + (float)bb[2]);
      float e3 = __expf(sc[t][3] + (float)bb[3]);
      sc[t][0] = e0; sc[t][1] = e1; sc[t][2] = e2; sc[t][3] = e3;
      rs += (e0 + e1) + (e2 + e3);
    }
    rs += __shfl_xor(rs, 16);
    rs += __shfl_xor(rs, 32);
    const float inv = 1.f / rs;

    // normalized P[q_local=l15][v] -> psw, b64 stores
    #pragma unroll
    for (int t = 0; t < 16; ++t) {
      bf16x4 o;
      o[0] = (bf16)(sc[t][0] * inv); o[1] = (bf16)(sc[t][1] * inv);
      o[2] = (bf16)(sc[t][2] * inv); o[3] = (bf16)(sc[t][3] * inv);
      *(bf16x4*)(psw + l15*264 + 16*t + 4*g) = o;
    }

    // PV: out^T[c][q] ; A = vF (coalesced), B = P (b128 LDS)
    f32x4 o0 = z, o1 = z;
    #pragma unroll
    for (int kt = 0; kt < 8; ++kt) {
      bf16x8 bp = *(const bf16x8*)(psw + l15*264 + 32*kt + 8*g);
      bf16x8 a0 = *(const bf16x8*)(vFh + ((size_t)(kt)*64 + lane)*8);
      bf16x8 a1 = *(const bf16x8*)(vFh + ((size_t)(8 + kt)*64 + lane)*8);
      o0 = MFMA(a0, bp, o0);
      o1 = MFMA(a1, bp, o1);
    }
    bf16x4 p0, p1;
    p0[0] = (bf16)o0[0]; p0[1] = (bf16)o0[1]; p0[2] = (bf16)o0[2]; p0[3] = (bf16)o0[3];
    p1[0] = (bf16)o1[0]; p1[1] = (bf16)o1[1]; p1[2] = (bf16)o1[2]; p1[3] = (bf16)o1[3];
    bf16* dst = aoh + ((size_t)rb + q0 + l15)*32;
    *(bf16x4*)(dst + 4*g)      = p0;
    *(bf16x4*)(dst + 16 + 4*g) = p1;
  }
}

// ---------------------------------------------------------------------------
// k_gate_out: out = (ao * gate) @ Wo + bo via MFMA; WoF frags hoisted.
// ---------------------------------------------------------------------------
__global__ __launch_bounds__(256) void k_gate_out(
    const bf16* __restrict__ aob, const bf16* __restrict__ gfb,
    const bf16* __restrict__ WoF, const float* __restrict__ bo,
    float* __restrict__ out)
{
  __shared__ bf16 gs[64 * 136];
  const int tid = threadIdx.x;
  const int base = blockIdx.x * 64;

  #pragma unroll
  for (int i = 0; i < 4; ++i) {
    const int flat = i*2048 + tid*8;
    const int pos = flat >> 7, c = flat & 127, h = c >> 5;
    bf16x8 a = *(const bf16x8*)(aob + ((size_t)h*P + base + pos)*32 + (c & 31));
    bf16x8 f = *(const bf16x8*)(gfb + ((size_t)(base + pos))*128 + c);
    bf16x8 o;
    #pragma unroll
    for (int j = 0; j < 8; ++j) o[j] = (bf16)((float)a[j] * (float)f[j]);
    *(bf16x8*)(gs + pos*136 + c) = o;
  }
  __syncthreads();

  const int w = tid >> 6, lane = tid & 63, g = lane >> 4, l15 = lane & 15;
  const f32x4 z = {0.f, 0.f, 0.f, 0.f};

  bf16x8 af[2][4];
  #pragma unroll
  for (int mi = 0; mi < 2; ++mi)
    #pragma unroll
    for (int kt = 0; kt < 4; ++kt)
      af[mi][kt] = *(const bf16x8*)(WoF + ((size_t)((2*w + mi)*4 + kt)*64 + lane)*8);

  for (int nt = 0; nt < 4; ++nt) {
    bf16x8 bfr[4];
    #pragma unroll
    for (int kt = 0; kt < 4; ++kt)
      bfr[kt] = *(const bf16x8*)(gs + (16*nt + l15)*136 + 32*kt + 8*g);
    f32x4 a0 = z, a1 = z;
    #pragma unroll
    for (int kt = 0; kt < 4; ++kt) {
      a0 = MFMA(af[0][kt], bfr[kt], a0);
      a1 = MFMA(af[1][kt], bfr[kt], a1);
    }
    const int pos = base + 16*nt + l15;
    {
      const int col = 16*(2*w + 0) + 4*g;
      float4 bb = *(const float4*)(bo + col);
      *(float4*)(out + (size_t)pos*128 + col) =
          make_float4(a0[0] + bb.x, a0[1] + bb.y, a0[2] + bb.z, a0[3] + bb.w);
    }
    {
      const int col = 16*(2*w + 1) + 4*g;
      float4 bb = *(const float4*)(bo + col);
      *(float4*)(out + (size_t)pos*128 + col) =
          make_float4(a1[0] + bb.x, a1[1] + bb.y, a1[2] + bb.z, a1[3] + bb.w);
    }
  }
}

// ---------------------------------------------------------------------------
extern "C" void kernel_launch(void* const* d_in, const int* in_sizes, int n_in,
                              void* d_out, int out_size, void* d_ws, size_t ws_size,
                              hipStream_t stream) {
  const float* pr    = (const float*)d_in[0];
  const float* mask  = (const float*)d_in[1];
  const float* gamma = (const float*)d_in[2];
  const float* beta  = (const float*)d_in[3];
  const float* Wq    = (const float*)d_in[4];
  const float* Wk    = (const float*)d_in[5];
  const float* Wv    = (const float*)d_in[6];
  const float* Wb    = (const float*)d_in[7];
  const float* Wfu   = (const float*)d_in[8];
  const float* bfu   = (const float*)d_in[9];
  const float* Wo    = (const float*)d_in[10];
  const float* bo    = (const float*)d_in[11];
  float* out = (float*)d_out;

  bf16* qbh = (bf16*)d_ws;                        // H*P*32
  bf16* kbh = qbh + (size_t)H * P * 32;
  bf16* vF  = kbh + (size_t)H * P * 32;           // [h][s][16 frag][64][8]
  bf16* gfb = vF  + (size_t)H * P * 32;           // P*128
  bf16* aob = gfb + (size_t)P * 128;              // H*P*32
  bf16* T6  = aob + (size_t)H * P * 32;           // H*16*16*64*4 = H*P
  bf16* WF  = T6  + (size_t)H * P;                // 4*16384
  bf16* WoF = WF  + 4 * 16384;                    // 16384
  bf16* WbF = WoF + 16384;                        // 2048
  float* pb = (float*)(WbF + 2048);               // [H][P] fp32

  k_prep<<<6, 256, 0, stream>>>(Wq, Wk, Wv, Wfu, Wo, Wb, WF, WoF, WbF);
  k_ln_proj<<<1024, 256, 0, stream>>>(pr, gamma, beta, bfu, WF, WbF,
                                      qbh, kbh, vF, gfb, pb);
  k_bias6<<<64, 256, 0, stream>>>(mask, pb, T6);
  k_attn<<<1024, 256, 0, stream>>>(qbh, kbh, vF, T6, aob);
  k_gate_out<<<1024, 256, 0, stream>>>(aob, gfb, WoF, bo, out);
}

// Round 5
// 201.100 us; speedup vs baseline: 1.0679x; 1.0679x over previous
//
#include <hip/hip_runtime.h>
#include <math.h>

#define L 256
#define E 128
#define H 4
#define C 32
#define P (L*L)  // 65536

typedef __bf16 bf16;
typedef __bf16 bf16x8 __attribute__((ext_vector_type(8)));
typedef __bf16 bf16x4 __attribute__((ext_vector_type(4)));
typedef float  f32x4  __attribute__((ext_vector_type(4)));

#define MFMA(a,b,c) __builtin_amdgcn_mfma_f32_16x16x32_bf16((a),(b),(c),0,0,0)

// ---------------------------------------------------------------------------
// k_prep: weights in MFMA A-fragment order. frag f=mt*4+kt; elem j at lane
// (g,l15) is A[row=16mt+l15][k=32kt+8g+j] = W[k][row] (*C^-0.5 for Wq).
// ---------------------------------------------------------------------------
__global__ __launch_bounds__(256) void k_prep(
    const float* __restrict__ Wq, const float* __restrict__ Wk,
    const float* __restrict__ Wv, const float* __restrict__ Wfu,
    const float* __restrict__ Wo, const float* __restrict__ Wb,
    bf16* __restrict__ WF, bf16* __restrict__ WoF, bf16* __restrict__ WbF)
{
  const int m = blockIdx.x;  // 0..5
  const int lane = threadIdx.x & 63, wv = threadIdx.x >> 6;
  const int g = lane >> 4, l15 = lane & 15;
  if (m < 5) {
    const float* W = (m==0)?Wq:(m==1)?Wk:(m==2)?Wv:(m==3)?Wfu:Wo;
    bf16* dst = (m < 4) ? (WF + (size_t)m * 16384) : WoF;
    const float sc = (m == 0) ? 0.17677669529663689f : 1.0f;
    for (int f = wv; f < 32; f += 4) {
      const int mt = f >> 2, kt = f & 3;
      const int row = 16*mt + l15, k0 = 32*kt + 8*g;
      bf16x8 o;
      #pragma unroll
      for (int j = 0; j < 8; ++j) o[j] = (bf16)(W[(size_t)(k0+j)*128 + row] * sc);
      *(bf16x8*)(dst + ((size_t)f*64 + lane)*8) = o;
    }
  } else {
    const int kt = wv, k0 = 32*kt + 8*g;
    bf16x8 o;
    #pragma unroll
    for (int j = 0; j < 8; ++j)
      o[j] = (l15 < 4) ? (bf16)Wb[(size_t)(k0+j)*4 + l15] : (bf16)0.0f;
    *(bf16x8*)(WbF + ((size_t)kt*64 + lane)*8) = o;
  }
}

// ---------------------------------------------------------------------------
// k_ln_proj: LN -> bf16 x in LDS; per-wave matrix (q,k,v,gate) via MFMA,
// 16 positions per pass (low VGPR). Wave 2 writes D-frags transposed into a
// [col][pos] LDS buffer and emits vF with b128 reads + 1KB-segment stores.
// Waves 0/1 store q/k head-major with one contiguous segment per head.
// ---------------------------------------------------------------------------
__global__ __launch_bounds__(256) void k_ln_proj(
    const float* __restrict__ pr, const float* __restrict__ gamma,
    const float* __restrict__ beta, const float* __restrict__ bfu,
    const bf16* __restrict__ WF, const bf16* __restrict__ WbF,
    bf16* __restrict__ qbh, bf16* __restrict__ kbh, bf16* __restrict__ vF,
    bf16* __restrict__ gfb, float* __restrict__ pbo)
{
  __shared__ bf16 xs[64 * 136];              // 17.0 KB
  __shared__ bf16 stg[3*2112 + 128*40];      // 22.4 KB (w0/w1/w3: 16x132; w2: 128x40)
  const int tid = threadIdx.x;
  const int base = blockIdx.x * 64;
  const int sblk = blockIdx.x >> 2;

  // --- LayerNorm (4 threads per position) ---
  {
    const int pl = tid >> 2, sub = tid & 3;
    const float4* src = (const float4*)(pr + (size_t)(base + pl) * 128 + sub * 32);
    float4 r[8];
    float s = 0.f, ss = 0.f;
    #pragma unroll
    for (int j = 0; j < 8; ++j) {
      r[j] = src[j];
      s  += r[j].x + r[j].y + r[j].z + r[j].w;
      ss += r[j].x*r[j].x + r[j].y*r[j].y + r[j].z*r[j].z + r[j].w*r[j].w;
    }
    s  += __shfl_xor(s, 1, 4);  s  += __shfl_xor(s, 2, 4);
    ss += __shfl_xor(ss, 1, 4); ss += __shfl_xor(ss, 2, 4);
    const float mu   = s * 0.0078125f;
    const float var  = ss * 0.0078125f - mu * mu;
    const float rstd = rsqrtf(var + 1e-5f);
    const float4* g4 = (const float4*)(gamma + sub * 32);
    const float4* b4 = (const float4*)(beta + sub * 32);
    bf16* xr = xs + pl * 136 + sub * 32;
    #pragma unroll
    for (int i = 0; i < 4; ++i) {
      float4 r0 = r[2*i], r1 = r[2*i+1];
      float4 gg0 = g4[2*i], gg1 = g4[2*i+1], bb0 = b4[2*i], bb1 = b4[2*i+1];
      bf16x8 o;
      o[0] = (bf16)((r0.x - mu) * rstd * gg0.x + bb0.x);
      o[1] = (bf16)((r0.y - mu) * rstd * gg0.y + bb0.y);
      o[2] = (bf16)((r0.z - mu) * rstd * gg0.z + bb0.z);
      o[3] = (bf16)((r0.w - mu) * rstd * gg0.w + bb0.w);
      o[4] = (bf16)((r1.x - mu) * rstd * gg1.x + bb1.x);
      o[5] = (bf16)((r1.y - mu) * rstd * gg1.y + bb1.y);
      o[6] = (bf16)((r1.z - mu) * rstd * gg1.z + bb1.z);
      o[7] = (bf16)((r1.w - mu) * rstd * gg1.w + bb1.w);
      *(bf16x8*)(xr + 8 * i) = o;
    }
  }
  __syncthreads();

  const int w = tid >> 6, lane = tid & 63, g = lane >> 4, l15 = lane & 15;
  const f32x4 z = {0.f, 0.f, 0.f, 0.f};

  // --- pair_bias via MFMA: wave w -> positions base+16w .. base+16w+15 ---
  {
    f32x4 acc = z;
    #pragma unroll
    for (int kt = 0; kt < 4; ++kt) {
      bf16x8 a = *(const bf16x8*)(WbF + ((size_t)kt*64 + lane)*8);
      bf16x8 b = *(const bf16x8*)(xs + (16*w + l15)*136 + 32*kt + 8*g);
      acc = MFMA(a, b, acc);
    }
    if (g == 0) {
      #pragma unroll
      for (int r = 0; r < 4; ++r)
        pbo[(size_t)r*P + base + 16*w + l15] = acc[r];
    }
  }

  // --- projection: wave w -> matrix w; 16 positions per pass ---
  const bf16* WFw = WF + (size_t)w * 16384;
  bf16* stw = stg + (w == 2 ? 6336 : (w == 3 ? 4224 : w*2112));

  for (int nt = 0; nt < 4; ++nt) {
    bf16x8 bfr[4];
    #pragma unroll
    for (int kt = 0; kt < 4; ++kt)
      bfr[kt] = *(const bf16x8*)(xs + (16*nt + l15)*136 + 32*kt + 8*g);
    f32x4 acc[8];
    #pragma unroll
    for (int mt = 0; mt < 8; ++mt) acc[mt] = z;
    #pragma unroll
    for (int kt = 0; kt < 4; ++kt)
      #pragma unroll
      for (int mt = 0; mt < 8; ++mt) {
        bf16x8 a = *(const bf16x8*)(WFw + ((size_t)(mt*4 + kt)*64 + lane)*8);
        acc[mt] = MFMA(a, bfr[kt], acc[mt]);
      }

    if (w == 2) {
      // transposed staging: stw[col(128)][pos32(40 pad)]
      const int ph = (nt & 1) * 16;
      #pragma unroll
      for (int mt = 0; mt < 8; ++mt) {
        const int col = 16*mt + 4*g;
        #pragma unroll
        for (int r = 0; r < 4; ++r)
          stw[(col + r)*40 + ph + l15] = (bf16)acc[mt][r];
      }
      if (nt & 1) {
        const int ktg = (blockIdx.x & 3)*2 + (nt >> 1);
        #pragma unroll
        for (int h2 = 0; h2 < 4; ++h2)
          #pragma unroll
          for (int mt2 = 0; mt2 < 2; ++mt2) {
            bf16x8 o = *(const bf16x8*)(stw + (h2*32 + 16*mt2 + l15)*40 + 8*g);
            *(bf16x8*)(vF + (((size_t)(h2*256 + sblk)*16 + mt2*8 + ktg)*64 + lane)*8) = o;
          }
      }
    } else {
      // epilogue -> LDS staging: stw[pos(16)][col(128), stride 132]
      #pragma unroll
      for (int mt = 0; mt < 8; ++mt) {
        const int col = 16*mt + 4*g;
        f32x4 vv = acc[mt];
        if (w == 3) {
          float4 bb = *(const float4*)(bfu + col);
          vv[0] = 1.f / (1.f + __expf(-(vv[0] + bb.x)));
          vv[1] = 1.f / (1.f + __expf(-(vv[1] + bb.y)));
          vv[2] = 1.f / (1.f + __expf(-(vv[2] + bb.z)));
          vv[3] = 1.f / (1.f + __expf(-(vv[3] + bb.w)));
        }
        bf16x4 o;
        o[0] = (bf16)vv[0]; o[1] = (bf16)vv[1]; o[2] = (bf16)vv[2]; o[3] = (bf16)vv[3];
        *(bf16x4*)(stw + l15*132 + col) = o;
      }
      if (w == 3) {
        #pragma unroll
        for (int i = 0; i < 4; ++i) {
          const int flat = i*512 + lane*8;
          const int p2 = flat >> 7, c = flat & 127;
          bf16x8 val = *(const bf16x8*)(stw + p2*132 + c);
          *(bf16x8*)(gfb + ((size_t)(base + 16*nt + p2))*128 + c) = val;
        }
      } else {
        bf16* dst = (w == 0) ? qbh : kbh;
        const int pos = lane >> 2, cc = (lane & 3)*8;
        #pragma unroll
        for (int h2 = 0; h2 < 4; ++h2) {
          bf16x8 val = *(const bf16x8*)(stw + pos*132 + h2*32 + cc);
          *(bf16x8*)(dst + ((size_t)h2*P + base + 16*nt + pos)*32 + cc) = val;
        }
      }
    }
  }
}

// ---------------------------------------------------------------------------
// k_bias6: T6[h][qblk(16)][t(16)][lane(64)][4] = mask[q,v] + pb[h][q*256+v]
// with q = qblk*16 + (lane&15), v = 16t + 4*(lane>>4) + r. Coalesced b64 out.
// ---------------------------------------------------------------------------
__global__ __launch_bounds__(256) void k_bias6(
    const float* __restrict__ mask, const float* __restrict__ pb,
    bf16* __restrict__ T6)
{
  const int b = blockIdx.x, h = b >> 4;
  const int lane = threadIdx.x & 63, tg = threadIdx.x >> 6;
  const int g = lane >> 4, l15 = lane & 15;
  const int q = (b & 15)*16 + l15;
  const float* mrow = mask + (size_t)q * 256;
  const float* prow = pb + (size_t)h * P + (size_t)q * 256;
  #pragma unroll
  for (int tt = 0; tt < 4; ++tt) {
    const int t = tg*4 + tt, v0 = 16*t + 4*g;
    float4 m4 = *(const float4*)(mrow + v0);
    float4 p4 = *(const float4*)(prow + v0);
    bf16x4 o;
    o[0] = (bf16)(m4.x + p4.x); o[1] = (bf16)(m4.y + p4.y);
    o[2] = (bf16)(m4.z + p4.z); o[3] = (bf16)(m4.w + p4.w);
    *(bf16x4*)(T6 + (((size_t)b*16 + t)*64 + lane)*4) = o;
  }
}

// ---------------------------------------------------------------------------
// k_attn: block=(s,h), 4 waves x 64 q-rows, no barriers. QK^T with A=qhat
// (reloaded per qt, L1/L2-hot), B=k. Scores processed in 2 halves of 8
// (sc[8] register pressure). Unnormalized exp to LDS; PV output scaled by
// 1/rowsum (valid: every PV lane's 4 values share one q).
// ---------------------------------------------------------------------------
__global__ __launch_bounds__(256) void k_attn(
    const bf16* __restrict__ qbh, const bf16* __restrict__ kbh,
    const bf16* __restrict__ vF, const bf16* __restrict__ T6,
    bf16* __restrict__ aob)
{
  __shared__ bf16 ps[4][16 * 264];    // 33.0 KB
  const int tid = threadIdx.x;
  const int s = blockIdx.x >> 2, h = blockIdx.x & 3;
  const int rb = s * 256;
  const int w = tid >> 6, lane = tid & 63, g = lane >> 4, l15 = lane & 15;
  const bf16* qh = qbh + (size_t)h * P * 32;
  const bf16* kh = kbh + (size_t)h * P * 32;
  const bf16* vFh = vF + ((size_t)(h*256 + s)*16)*512;
  bf16* psw = ps[w];
  bf16* aoh = aob + (size_t)h * P * 32;
  const f32x4 z = {0.f, 0.f, 0.f, 0.f};

  for (int qt = 0; qt < 4; ++qt) {
    const int q0 = w*64 + qt*16;

    // B = k for 16 q rows
    bf16x8 bk = *(const bf16x8*)(kh + ((size_t)rb + q0 + l15)*32 + 8*g);

    const bf16* Tq = T6 + ((size_t)(h*16 + w*4 + qt)*16)*256;
    float rs = 0.f;
    #pragma unroll
    for (int hh = 0; hh < 2; ++hh) {
      f32x4 sc[8];
      #pragma unroll
      for (int tt = 0; tt < 8; ++tt) {
        const int t = 8*hh + tt;
        bf16x8 aq = *(const bf16x8*)(qh + ((size_t)rb + 16*t + l15)*32 + 8*g);
        sc[tt] = MFMA(aq, bk, z);
      }
      #pragma unroll
      for (int tt = 0; tt < 8; ++tt) {
        const int t = 8*hh + tt;
        bf16x4 bb = *(const bf16x4*)(Tq + ((size_t)t*64 + lane)*4);
        float e0 = __expf(sc[tt][0] + (float)bb[0]);
        float e1 = __expf(sc[tt][1] + (float)bb[1]);
        float e2 = __expf(sc[tt][2] + (float)bb[2]);
        float e3 = __expf(sc[tt][3] + (float)bb[3]);
        rs += (e0 + e1) + (e2 + e3);
        bf16x4 o;
        o[0] = (bf16)e0; o[1] = (bf16)e1; o[2] = (bf16)e2; o[3] = (bf16)e3;
        *(bf16x4*)(psw + l15*264 + 16*t + 4*g) = o;
      }
    }
    rs += __shfl_xor(rs, 16);
    rs += __shfl_xor(rs, 32);
    const float inv = 1.f / rs;

    // PV: out^T[c][q]; A = vF (coalesced, L1-hot), B = raw-exp P (LDS b128)
    f32x4 o0 = z, o1 = z;
    #pragma unroll
    for (int kt = 0; kt < 8; ++kt) {
      bf16x8 bp = *(const bf16x8*)(psw + l15*264 + 32*kt + 8*g);
      bf16x8 a0 = *(const bf16x8*)(vFh + ((size_t)(kt)*64 + lane)*8);
      bf16x8 a1 = *(const bf16x8*)(vFh + ((size_t)(8 + kt)*64 + lane)*8);
      o0 = MFMA(a0, bp, o0);
      o1 = MFMA(a1, bp, o1);
    }
    bf16x4 p0, p1;
    p0[0] = (bf16)(o0[0]*inv); p0[1] = (bf16)(o0[1]*inv);
    p0[2] = (bf16)(o0[2]*inv); p0[3] = (bf16)(o0[3]*inv);
    p1[0] = (bf16)(o1[0]*inv); p1[1] = (bf16)(o1[1]*inv);
    p1[2] = (bf16)(o1[2]*inv); p1[3] = (bf16)(o1[3]*inv);
    bf16* dst = aoh + ((size_t)rb + q0 + l15)*32;
    *(bf16x4*)(dst + 4*g)      = p0;
    *(bf16x4*)(dst + 16 + 4*g) = p1;
  }
}

// ---------------------------------------------------------------------------
// k_gate_out: out = (ao * gate) @ Wo + bo via MFMA; WoF frags hoisted.
// ---------------------------------------------------------------------------
__global__ __launch_bounds__(256) void k_gate_out(
    const bf16* __restrict__ aob, const bf16* __restrict__ gfb,
    const bf16* __restrict__ WoF, const float* __restrict__ bo,
    float* __restrict__ out)
{
  __shared__ bf16 gs[64 * 136];
  const int tid = threadIdx.x;
  const int base = blockIdx.x * 64;

  #pragma unroll
  for (int i = 0; i < 4; ++i) {
    const int flat = i*2048 + tid*8;
    const int pos = flat >> 7, c = flat & 127, h = c >> 5;
    bf16x8 a = *(const bf16x8*)(aob + ((size_t)h*P + base + pos)*32 + (c & 31));
    bf16x8 f = *(const bf16x8*)(gfb + ((size_t)(base + pos))*128 + c);
    bf16x8 o;
    #pragma unroll
    for (int j = 0; j < 8; ++j) o[j] = (bf16)((float)a[j] * (float)f[j]);
    *(bf16x8*)(gs + pos*136 + c) = o;
  }
  __syncthreads();

  const int w = tid >> 6, lane = tid & 63, g = lane >> 4, l15 = lane & 15;
  const f32x4 z = {0.f, 0.f, 0.f, 0.f};

  bf16x8 af[2][4];
  #pragma unroll
  for (int mi = 0; mi < 2; ++mi)
    #pragma unroll
    for (int kt = 0; kt < 4; ++kt)
      af[mi][kt] = *(const bf16x8*)(WoF + ((size_t)((2*w + mi)*4 + kt)*64 + lane)*8);

  for (int nt = 0; nt < 4; ++nt) {
    bf16x8 bfr[4];
    #pragma unroll
    for (int kt = 0; kt < 4; ++kt)
      bfr[kt] = *(const bf16x8*)(gs + (16*nt + l15)*136 + 32*kt + 8*g);
    f32x4 a0 = z, a1 = z;
    #pragma unroll
    for (int kt = 0; kt < 4; ++kt) {
      a0 = MFMA(af[0][kt], bfr[kt], a0);
      a1 = MFMA(af[1][kt], bfr[kt], a1);
    }
    const int pos = base + 16*nt + l15;
    {
      const int col = 16*(2*w + 0) + 4*g;
      float4 bb = *(const float4*)(bo + col);
      *(float4*)(out + (size_t)pos*128 + col) =
          make_float4(a0[0] + bb.x, a0[1] + bb.y, a0[2] + bb.z, a0[3] + bb.w);
    }
    {
      const int col = 16*(2*w + 1) + 4*g;
      float4 bb = *(const float4*)(bo + col);
      *(float4*)(out + (size_t)pos*128 + col) =
          make_float4(a1[0] + bb.x, a1[1] + bb.y, a1[2] + bb.z, a1[3] + bb.w);
    }
  }
}

// ---------------------------------------------------------------------------
extern "C" void kernel_launch(void* const* d_in, const int* in_sizes, int n_in,
                              void* d_out, int out_size, void* d_ws, size_t ws_size,
                              hipStream_t stream) {
  const float* pr    = (const float*)d_in[0];
  const float* mask  = (const float*)d_in[1];
  const float* gamma = (const float*)d_in[2];
  const float* beta  = (const float*)d_in[3];
  const float* Wq    = (const float*)d_in[4];
  const float* Wk    = (const float*)d_in[5];
  const float* Wv    = (const float*)d_in[6];
  const float* Wb    = (const float*)d_in[7];
  const float* Wfu   = (const float*)d_in[8];
  const float* bfu   = (const float*)d_in[9];
  const float* Wo    = (const float*)d_in[10];
  const float* bo    = (const float*)d_in[11];
  float* out = (float*)d_out;

  bf16* qbh = (bf16*)d_ws;                        // H*P*32
  bf16* kbh = qbh + (size_t)H * P * 32;
  bf16* vF  = kbh + (size_t)H * P * 32;           // [h][s][16 frag][64][8]
  bf16* gfb = vF  + (size_t)H * P * 32;           // P*128
  bf16* aob = gfb + (size_t)P * 128;              // H*P*32
  bf16* T6  = aob + (size_t)H * P * 32;           // H*16*16*64*4 = H*P
  bf16* WF  = T6  + (size_t)H * P;                // 4*16384
  bf16* WoF = WF  + 4 * 16384;                    // 16384
  bf16* WbF = WoF + 16384;                        // 2048
  float* pb = (float*)(WbF + 2048);               // [H][P] fp32

  k_prep<<<6, 256, 0, stream>>>(Wq, Wk, Wv, Wfu, Wo, Wb, WF, WoF, WbF);
  k_ln_proj<<<1024, 256, 0, stream>>>(pr, gamma, beta, bfu, WF, WbF,
                                      qbh, kbh, vF, gfb, pb);
  k_bias6<<<64, 256, 0, stream>>>(mask, pb, T6);
  k_attn<<<1024, 256, 0, stream>>>(qbh, kbh, vF, T6, aob);
  k_gate_out<<<1024, 256, 0, stream>>>(aob, gfb, WoF, bo, out);
}